// Round 1
// baseline (97.126 us; speedup 1.0000x reference)
//
#include <hip/hip_runtime.h>
#include <hip/hip_bf16.h>

// Problem: B=8, S=4096, D=1024. Inputs: x0[B,S,D] f32, x1[B,S,D] f32,
// skipping_probs[B,S] f32 (unused — keep mask already sampled), keep[B,S] i32.
// Output: two [B,S,D] f32 tensors, concatenated flat in d_out: kept rows
// compacted to the front (stable order), tail rows zeroed.

#define BB 8
#define SS 4096
#define DD 1024
#define D4 (DD / 4)   // 256 float4 per row

// ---------------- Kernel A: per-batch stable compaction index ----------------
// grid = B blocks, 1024 threads. Each thread owns 4 consecutive timesteps.
// Produces src_idx[b*S + r] = source timestep of the r-th kept row, and
// n_kept[b]. Stable: scan is in timestep order.
__global__ __launch_bounds__(1024) void scan_kernel(
    const int* __restrict__ keep,
    int* __restrict__ src_idx,
    int* __restrict__ n_kept)
{
    const int b = blockIdx.x;
    const int t = threadIdx.x;           // 0..1023
    __shared__ int wave_sums[16];

    const int* krow = keep + b * SS;
    const int base = t * 4;
    const int k0 = krow[base + 0];
    const int k1 = krow[base + 1];
    const int k2 = krow[base + 2];
    const int k3 = krow[base + 3];
    const int local = k0 + k1 + k2 + k3;

    const int lane = t & 63;
    const int wid  = t >> 6;             // 0..15

    // wave-inclusive scan of per-thread totals (64 lanes)
    int incl = local;
    #pragma unroll
    for (int off = 1; off < 64; off <<= 1) {
        int v = __shfl_up(incl, off, 64);
        if (lane >= off) incl += v;
    }
    if (lane == 63) wave_sums[wid] = incl;
    __syncthreads();

    // inclusive scan of the 16 wave totals (lanes 0..15 of wave 0)
    if (t < 16) {
        int v = wave_sums[t];
        #pragma unroll
        for (int off = 1; off < 16; off <<= 1) {
            int u = __shfl_up(v, off, 64);
            if (t >= off) v += u;
        }
        wave_sums[t] = v;
    }
    __syncthreads();

    const int wave_off = (wid > 0) ? wave_sums[wid - 1] : 0;
    int d = wave_off + incl - local;     // exclusive prefix for this thread's 4

    int* dst = src_idx + b * SS;
    if (k0) dst[d++] = base + 0;
    if (k1) dst[d++] = base + 1;
    if (k2) dst[d++] = base + 2;
    if (k3) dst[d++] = base + 3;

    if (t == 0) n_kept[b] = wave_sums[15];
}

// ---------------- Kernel B: destination-indexed row copy ----------------
// grid = B*S blocks (one per output row), 256 threads (one float4 each,
// 256*16B = 4096B = one full row). Rows r < n_kept[b] gather their source
// row for both tensors; tail rows write zeros. Each output element written
// exactly once -> no separate zero pass, deterministic across replays.
__global__ __launch_bounds__(256) void compact_copy_kernel(
    const float4* __restrict__ x0,
    const float4* __restrict__ x1,
    const int* __restrict__ src_idx,
    const int* __restrict__ n_kept,
    float4* __restrict__ out0,
    float4* __restrict__ out1)
{
    const int row = blockIdx.x;          // 0 .. B*S-1
    const int b   = row >> 12;           // / 4096
    const int r   = row & (SS - 1);
    const int t   = threadIdx.x;         // 0..255

    const int nk = n_kept[b];
    const int dst_off = row * D4 + t;

    if (r < nk) {
        const int s = src_idx[row];
        const int src_off = (b * SS + s) * D4 + t;
        out0[dst_off] = x0[src_off];
        out1[dst_off] = x1[src_off];
    } else {
        const float4 z = make_float4(0.f, 0.f, 0.f, 0.f);
        out0[dst_off] = z;
        out1[dst_off] = z;
    }
}

extern "C" void kernel_launch(void* const* d_in, const int* in_sizes, int n_in,
                              void* d_out, int out_size, void* d_ws, size_t ws_size,
                              hipStream_t stream) {
    const float4* x0  = (const float4*)d_in[0];
    const float4* x1  = (const float4*)d_in[1];
    // d_in[2] = skipping_probs (unused: keep mask is pre-sampled)
    const int* keep   = (const int*)d_in[3];

    float* out = (float*)d_out;
    float4* out0 = (float4*)out;
    float4* out1 = (float4*)(out + (size_t)BB * SS * DD);

    int* src_idx = (int*)d_ws;                 // B*S ints = 128 KiB
    int* n_kept  = src_idx + BB * SS;          // B ints

    scan_kernel<<<BB, 1024, 0, stream>>>(keep, src_idx, n_kept);
    compact_copy_kernel<<<BB * SS, 256, 0, stream>>>(x0, x1, src_idx, n_kept,
                                                     out0, out1);
}

// Round 2
// 92.135 us; speedup vs baseline: 1.0542x; 1.0542x over previous
//
#include <hip/hip_runtime.h>
#include <hip/hip_bf16.h>

// Problem: B=8, S=4096, D=1024. Inputs: x0[B,S,D] f32, x1[B,S,D] f32,
// skipping_probs[B,S] f32 (unused — keep mask already sampled), keep[B,S] i32.
// Output: two [B,S,D] f32 tensors, concatenated flat in d_out: kept rows
// compacted to the front (stable order), tail rows zeroed.
//
// Pure data movement. Minimal traffic: 268 MB writes + ~201 MB reads (~75% keep
// rate). Streaming with zero reuse -> non-temporal loads/stores to bypass L2.

#define BB 8
#define SS 4096
#define DD 1024
#define D4 (DD / 4)   // 256 float4 per row

typedef float f4 __attribute__((ext_vector_type(4)));

// ---------------- Kernel A: per-batch stable compaction index ----------------
// grid = B blocks, 1024 threads. Each thread owns 4 consecutive timesteps.
// Produces src_idx[b*S + r] = source timestep of the r-th kept row, and
// n_kept[b]. Stable: scan is in timestep order.
__global__ __launch_bounds__(1024) void scan_kernel(
    const int* __restrict__ keep,
    int* __restrict__ src_idx,
    int* __restrict__ n_kept)
{
    const int b = blockIdx.x;
    const int t = threadIdx.x;           // 0..1023
    __shared__ int wave_sums[16];

    const int* krow = keep + b * SS;
    const int base = t * 4;
    const int k0 = krow[base + 0];
    const int k1 = krow[base + 1];
    const int k2 = krow[base + 2];
    const int k3 = krow[base + 3];
    const int local = k0 + k1 + k2 + k3;

    const int lane = t & 63;
    const int wid  = t >> 6;             // 0..15

    // wave-inclusive scan of per-thread totals (64 lanes)
    int incl = local;
    #pragma unroll
    for (int off = 1; off < 64; off <<= 1) {
        int v = __shfl_up(incl, off, 64);
        if (lane >= off) incl += v;
    }
    if (lane == 63) wave_sums[wid] = incl;
    __syncthreads();

    // inclusive scan of the 16 wave totals (lanes 0..15 of wave 0)
    if (t < 16) {
        int v = wave_sums[t];
        #pragma unroll
        for (int off = 1; off < 16; off <<= 1) {
            int u = __shfl_up(v, off, 64);
            if (t >= off) v += u;
        }
        wave_sums[t] = v;
    }
    __syncthreads();

    const int wave_off = (wid > 0) ? wave_sums[wid - 1] : 0;
    int d = wave_off + incl - local;     // exclusive prefix for this thread's 4

    int* dst = src_idx + b * SS;
    if (k0) dst[d++] = base + 0;
    if (k1) dst[d++] = base + 1;
    if (k2) dst[d++] = base + 2;
    if (k3) dst[d++] = base + 3;

    if (t == 0) n_kept[b] = wave_sums[15];
}

// ---------------- Kernel B: destination-indexed row copy ----------------
// Grid-stride over output rows: 2048 blocks x 256 threads (8 blocks/CU),
// each block handles 16 rows. Per row: 256 threads x 1 float4 per tensor
// (256*16B = 4 KiB = one full row). Rows r < n_kept[b] gather their source
// row for both tensors; tail rows write zeros. Every output element written
// exactly once per call -> deterministic across graph replays.
#define COPY_BLOCKS 2048
__global__ __launch_bounds__(256) void compact_copy_kernel(
    const f4* __restrict__ x0,
    const f4* __restrict__ x1,
    const int* __restrict__ src_idx,
    const int* __restrict__ n_kept,
    f4* __restrict__ out0,
    f4* __restrict__ out1)
{
    const int t = threadIdx.x;           // 0..255

    for (int row = blockIdx.x; row < BB * SS; row += COPY_BLOCKS) {
        const int b = row >> 12;         // / 4096
        const int r = row & (SS - 1);
        const int nk = n_kept[b];
        const int dst_off = row * D4 + t;

        if (r < nk) {
            const int s = src_idx[row];
            const int src_off = (b * SS + s) * D4 + t;
            f4 v0 = __builtin_nontemporal_load(&x0[src_off]);
            f4 v1 = __builtin_nontemporal_load(&x1[src_off]);
            __builtin_nontemporal_store(v0, &out0[dst_off]);
            __builtin_nontemporal_store(v1, &out1[dst_off]);
        } else {
            f4 z = {0.f, 0.f, 0.f, 0.f};
            __builtin_nontemporal_store(z, &out0[dst_off]);
            __builtin_nontemporal_store(z, &out1[dst_off]);
        }
    }
}

extern "C" void kernel_launch(void* const* d_in, const int* in_sizes, int n_in,
                              void* d_out, int out_size, void* d_ws, size_t ws_size,
                              hipStream_t stream) {
    const f4* x0  = (const f4*)d_in[0];
    const f4* x1  = (const f4*)d_in[1];
    // d_in[2] = skipping_probs (unused: keep mask is pre-sampled)
    const int* keep = (const int*)d_in[3];

    float* out = (float*)d_out;
    f4* out0 = (f4*)out;
    f4* out1 = (f4*)(out + (size_t)BB * SS * DD);

    int* src_idx = (int*)d_ws;                 // B*S ints = 128 KiB
    int* n_kept  = src_idx + BB * SS;          // B ints

    scan_kernel<<<BB, 1024, 0, stream>>>(keep, src_idx, n_kept);
    compact_copy_kernel<<<COPY_BLOCKS, 256, 0, stream>>>(x0, x1, src_idx, n_kept,
                                                         out0, out1);
}